// Round 4
// baseline (91.346 us; speedup 1.0000x reference)
//
#include <hip/hip_runtime.h>
#include <math.h>

// CrowdDet RetinaNet loss constants
#define POS_T 0.5f
#define NEG_T 0.4f
#define F_ALPHA 0.25f
#define SL1_BETA 0.1f

// d_ws layout:
//   bytes [0,24)     : 3 doubles (loss_cls, loss_reg, num_pos accumulators)
//   bytes [512, ...) : prepped GT data, stride 8 floats per gt:
//                      {g0, g1, g2+1, g3+1, area_g, cls, g2, g3}
#define WS_GT_BYTE_OFF 512

__device__ __forceinline__ float smooth_l1(float d) {
    d = fabsf(d);
    return d < SL1_BETA ? 0.5f * d * d / SL1_BETA : d - SL1_BETA;
}

// Prep: build stride-8 GT records AND zero the ws accumulators (one less node).
__global__ void prep_gt_kernel(const float* __restrict__ gt, float* __restrict__ gtp,
                               double* __restrict__ ws, int total) {
#pragma clang fp contract(off)
    const int i = blockIdx.x * 256 + threadIdx.x;
    if (i < 3) ws[i] = 0.0;
    if (i < total) {
        const float* s = gt + (size_t)i * 5;
        const float g0 = s[0], g1 = s[1], g2 = s[2], g3 = s[3], cls = s[4];
        // area with exact reference op order: ((g2-g0)+1) * ((g3-g1)+1)
        const float area_g = (g2 - g0 + 1.f) * (g3 - g1 + 1.f);
        float4* d = reinterpret_cast<float4*>(gtp + (size_t)i * 8);
        d[0] = make_float4(g0, g1, g2 + 1.f, g3 + 1.f);   // pre-added +1 for iw/ih
        d[1] = make_float4(area_g, cls, g2, g3);          // originals for epilogue
    }
}

// 1 anchor/thread; GT tile staged in LDS, read via wave-uniform broadcast.
__global__ __launch_bounds__(256) void retina_loss_kernel(
    const float* __restrict__ pred_cls,   // [B,A,1]
    const float* __restrict__ pred_reg,   // [B,A,4]
    const float* __restrict__ anchors,    // [A,4]
    const float* __restrict__ im_info,    // [B,6]
    const float* __restrict__ gtp_all,    // [B,G,8] prepped
    int A, int G,
    double* __restrict__ ws)
{
#pragma clang fp contract(off)
    extern __shared__ float sgt[];        // G*8 floats

    const int b = blockIdx.y;
    const int a_raw = blockIdx.x * 256 + threadIdx.x;
    const bool live = a_raw < A;
    const int a = min(a_raw, A - 1);      // clamp: uniform control flow, in-bounds
    const float* __restrict__ gtp = gtp_all + (size_t)b * G * 8;
    // SGPR trip count -> uniform loop.
    const int nvalid = __builtin_amdgcn_readfirstlane((int)im_info[b * 6 + 5]);

    // Cooperative stage: nvalid*2 float4s (<= 600) into LDS.
    for (int i = threadIdx.x; i < nvalid * 2; i += 256) {
        reinterpret_cast<float4*>(sgt)[i] =
            reinterpret_cast<const float4*>(gtp)[i];
    }

    const float4 anc = *reinterpret_cast<const float4*>(anchors + 4 * (size_t)a);
    const float a0 = anc.x, a1 = anc.y, a2 = anc.z, a3 = anc.w;
    const float aw = a2 - a0 + 1.f;
    const float ah = a3 - a1 + 1.f;
    const float area_a = aw * ah;
    const float a2p = a2 + 1.f;           // pre-added +1 (bit-exact vs ref, see note)
    const float a3p = a3 + 1.f;

    __syncthreads();

    // Division-free IoU argmax: iou = inter/(S-inter) monotone in inter/S =>
    // iou_i > iou_j  <=>  inter_i*S_j > inter_j*S_i (S>0). Init (-1,1) makes
    // the first gt always win; strict > == first-max (jnp.argmax tie-break).
    // iw = min(a2,g2)-max(a0,g0)+1 == min(a2+1,g2+1)-max(a0,g0): rounding of
    // x+1 is monotone, so the +1 commutes with min bit-exactly.
    float best_inter = -1.f, best_S = 1.f;
    int arg = 0;
    #pragma unroll 8
    for (int g = 0; g < nvalid; ++g) {
        const float* gp = sgt + g * 8;                       // uniform -> broadcast
        const float4 gb = *reinterpret_cast<const float4*>(gp);  // ds_read_b128
        const float sg = gp[4];                                  // ds_read_b32
        const float iw = fminf(a2p, gb.z) - fmaxf(a0, gb.x);
        const float ih = fminf(a3p, gb.w) - fmaxf(a1, gb.y);
        const float inter = fmaxf(iw, 0.f) * fmaxf(ih, 0.f);
        const float S = area_a + sg;
        const bool upd = inter * best_S > best_inter * S;
        best_inter = upd ? inter : best_inter;
        best_S     = upd ? S     : best_S;
        arg        = upd ? g     : arg;
    }

    float lc = 0.f, lr = 0.f;
    int fg = 0;

    if (live) {
        // ONE division, exact reference expression: inter/((area_a+area_g)-inter)
        const float max_ov = best_inter / (best_S - best_inter);

        float label = 0.f;
        bool valid = true;
        if (max_ov >= POS_T) {
            label = sgt[(size_t)arg * 8 + 5];
        } else if (max_ov >= NEG_T) {
            valid = false;                 // ignore band
        }
        fg = (label > 0.f) ? 1 : 0;

        if (valid) {
            const float x = pred_cls[(size_t)b * A + a];
            const float p = 1.f / (1.f + expf(-x));
            const float l1p = log1pf(expf(-fabsf(x)));
            const float log_p  = fminf(x, 0.f) - l1p;    // log_sigmoid(x)
            const float log_np = fminf(-x, 0.f) - l1p;   // log_sigmoid(-x)
            const float pos = (label == 1.f) ? 1.f : 0.f;
            const float omp = 1.f - p;
            lc = -(F_ALPHA * pos * (omp * omp) * log_p
                   + (1.f - F_ALPHA) * (1.f - pos) * (p * p) * log_np);
        }

        if (fg) {
            const float g0 = sgt[(size_t)arg * 8 + 0];
            const float g1 = sgt[(size_t)arg * 8 + 1];
            const float g2 = sgt[(size_t)arg * 8 + 6];   // original g2
            const float g3 = sgt[(size_t)arg * 8 + 7];   // original g3
            const float gw = g2 - g0 + 1.f;
            const float gh = g3 - g1 + 1.f;
            const float gx = g0 + 0.5f * gw;
            const float gy = g1 + 0.5f * gh;
            const float axc = a0 + 0.5f * aw;
            const float ayc = a1 + 0.5f * ah;
            const float t0 = (gx - axc) / aw;
            const float t1 = (gy - ayc) / ah;
            const float t2 = logf(gw / aw);
            const float t3 = logf(gh / ah);
            const float4 r = *reinterpret_cast<const float4*>(
                pred_reg + 4 * ((size_t)b * A + a));
            lr = smooth_l1(r.x - t0) + smooth_l1(r.y - t1)
               + smooth_l1(r.z - t2) + smooth_l1(r.w - t3);
        }
    }

    // wave64 reduction
    for (int off = 32; off > 0; off >>= 1) {
        lc += __shfl_down(lc, off);
        lr += __shfl_down(lr, off);
        fg += __shfl_down(fg, off);
    }

    __shared__ float s_lc[4], s_lr[4];
    __shared__ int s_np[4];
    const int wid = threadIdx.x >> 6;
    const int lane = threadIdx.x & 63;
    if (lane == 0) { s_lc[wid] = lc; s_lr[wid] = lr; s_np[wid] = fg; }
    __syncthreads();
    if (threadIdx.x == 0) {
        const float tlc = s_lc[0] + s_lc[1] + s_lc[2] + s_lc[3];
        const float tlr = s_lr[0] + s_lr[1] + s_lr[2] + s_lr[3];
        const int   tnp = s_np[0] + s_np[1] + s_np[2] + s_np[3];
        __hip_atomic_fetch_add(&ws[0], (double)tlc, __ATOMIC_RELAXED, __HIP_MEMORY_SCOPE_AGENT);
        __hip_atomic_fetch_add(&ws[1], (double)tlr, __ATOMIC_RELAXED, __HIP_MEMORY_SCOPE_AGENT);
        __hip_atomic_fetch_add(&ws[2], (double)tnp, __ATOMIC_RELAXED, __HIP_MEMORY_SCOPE_AGENT);
    }
}

__global__ void finalize_kernel(const double* __restrict__ ws, float* __restrict__ out) {
    if (threadIdx.x == 0 && blockIdx.x == 0) {
        const double npos = ws[2] < 1.0 ? 1.0 : ws[2];
        const double norm = 0.9 * 100.0 + 0.1 * npos;
        out[0] = (float)(ws[0] / norm);
        out[1] = (float)(ws[1] / norm);
    }
}

extern "C" void kernel_launch(void* const* d_in, const int* in_sizes, int n_in,
                              void* d_out, int out_size, void* d_ws, size_t ws_size,
                              hipStream_t stream) {
    const float* pred_cls = (const float*)d_in[0];
    const float* pred_reg = (const float*)d_in[1];
    const float* anchors  = (const float*)d_in[2];
    const float* gt_boxes = (const float*)d_in[3];
    const float* im_info  = (const float*)d_in[4];

    const int A = in_sizes[2] / 4;
    const int B = in_sizes[4] / 6;
    const int G = in_sizes[3] / (B * 5);

    double* ws = (double*)d_ws;
    float*  gtp = (float*)((char*)d_ws + WS_GT_BYTE_OFF);

    const int total_gt = B * G;
    prep_gt_kernel<<<(total_gt + 255) / 256, 256, 0, stream>>>(gt_boxes, gtp, ws, total_gt);

    const size_t shmem = (size_t)G * 8 * sizeof(float);   // 9.6 KB for G=300
    dim3 grid((A + 255) / 256, B);
    retina_loss_kernel<<<grid, 256, shmem, stream>>>(
        pred_cls, pred_reg, anchors, im_info, gtp, A, G, ws);
    finalize_kernel<<<1, 1, 0, stream>>>(ws, (float*)d_out);
}

// Round 5
// 82.990 us; speedup vs baseline: 1.1007x; 1.1007x over previous
//
#include <hip/hip_runtime.h>
#include <math.h>

// CrowdDet RetinaNet loss constants
#define POS_T 0.5f
#define NEG_T 0.4f
#define F_ALPHA 0.25f
#define SL1_BETA 0.1f
#define SENT 3.0e8f

// d_ws layout:
//   bytes [0,24)     : 3 doubles (loss_cls, loss_reg, num_pos accumulators)
//   bytes [512, ...) : prepped GT records, stride 8 floats, padded to Gp/batch:
//                      {g0, g1, g2+1, g3+1, area_g, cls, g2, g3}
//                      j >= nvalid -> sentinel far-away box (never wins argmax)
#define WS_GT_BYTE_OFF 512

__device__ __forceinline__ float smooth_l1(float d) {
    d = fabsf(d);
    return d < SL1_BETA ? 0.5f * d * d / SL1_BETA : d - SL1_BETA;
}

// Force a (wave-uniform) float into an SGPR.
__device__ __forceinline__ float rflf(float x) {
    return __int_as_float(__builtin_amdgcn_readfirstlane(__float_as_int(x)));
}

__global__ void prep_gt_kernel(const float* __restrict__ gt,
                               const float* __restrict__ im_info,
                               float* __restrict__ gtp, double* __restrict__ ws,
                               int G, int Gp, int B) {
#pragma clang fp contract(off)
    const int i = blockIdx.x * 256 + threadIdx.x;
    if (i < 3) ws[i] = 0.0;
    const int total = B * Gp;
    if (i >= total) return;
    const int b = i / Gp, j = i - b * Gp;
    const int nv = (int)im_info[b * 6 + 5];
    float4 lo, hi;
    if (j < nv) {
        const float* s = gt + ((size_t)b * G + j) * 5;
        const float g0 = s[0], g1 = s[1], g2 = s[2], g3 = s[3], cls = s[4];
        const float area_g = (g2 - g0 + 1.f) * (g3 - g1 + 1.f);  // exact ref order
        lo = make_float4(g0, g1, g2 + 1.f, g3 + 1.f);   // pre-added +1 for iw/ih
        hi = make_float4(area_g, cls, g2, g3);          // originals for epilogue
    } else {
        // Sentinel: zero intersection with any real anchor; can never win.
        lo = make_float4(SENT, SENT, SENT + 2.f, SENT + 2.f);
        hi = make_float4(4.f, 0.f, SENT + 1.f, SENT + 1.f);
    }
    float4* d = reinterpret_cast<float4*>(gtp + (size_t)i * 8);
    d[0] = lo; d[1] = hi;
}

// Per-anchor epilogue: focal + smooth-L1 contributions.
__device__ __forceinline__ void epilogue(
    bool live, float a0, float a1, float aw, float ah,
    float best_inter, float best_S, int arg,
    const float* __restrict__ gtp,
    const float* __restrict__ pred_cls_elem,
    const float* __restrict__ pred_reg_elem,
    float& lc, float& lr, int& fg)
{
#pragma clang fp contract(off)
    if (!live) return;
    // ONE division, exact reference expression: inter/((area_a+area_g)-inter)
    const float max_ov = best_inter / (best_S - best_inter);

    float label = 0.f;
    bool valid = true;
    if (max_ov >= POS_T) {
        label = gtp[(size_t)arg * 8 + 5];
    } else if (max_ov >= NEG_T) {
        valid = false;                       // ignore band
    }
    const int f = (label > 0.f) ? 1 : 0;
    fg += f;

    if (valid) {
        const float x = *pred_cls_elem;
        const float p = 1.f / (1.f + expf(-x));
        const float l1p = log1pf(expf(-fabsf(x)));
        const float log_p  = fminf(x, 0.f) - l1p;    // log_sigmoid(x)
        const float log_np = fminf(-x, 0.f) - l1p;   // log_sigmoid(-x)
        const float pos = (label == 1.f) ? 1.f : 0.f;
        const float omp = 1.f - p;
        lc += -(F_ALPHA * pos * (omp * omp) * log_p
                + (1.f - F_ALPHA) * (1.f - pos) * (p * p) * log_np);
    }

    if (f) {
        const float g0 = gtp[(size_t)arg * 8 + 0];
        const float g1 = gtp[(size_t)arg * 8 + 1];
        const float g2 = gtp[(size_t)arg * 8 + 6];   // original g2
        const float g3 = gtp[(size_t)arg * 8 + 7];   // original g3
        const float gw = g2 - g0 + 1.f;
        const float gh = g3 - g1 + 1.f;
        const float gx = g0 + 0.5f * gw;
        const float gy = g1 + 0.5f * gh;
        const float axc = a0 + 0.5f * aw;
        const float ayc = a1 + 0.5f * ah;
        const float t0 = (gx - axc) / aw;
        const float t1 = (gy - ayc) / ah;
        const float t2 = logf(gw / aw);
        const float t3 = logf(gh / ah);
        const float4 r = *reinterpret_cast<const float4*>(pred_reg_elem);
        lr += smooth_l1(r.x - t0) + smooth_l1(r.y - t1)
            + smooth_l1(r.z - t2) + smooth_l1(r.w - t3);
    }
}

// 2 anchors/thread. GT tile (4 gts) broadcast-loaded from L1 and pinned into
// SGPRs via readfirstlane -> inner loop is pure VALU with SGPR operands.
__global__ __launch_bounds__(256) void retina_loss_kernel(
    const float* __restrict__ pred_cls,   // [B,A,1]
    const float* __restrict__ pred_reg,   // [B,A,4]
    const float* __restrict__ anchors,    // [A,4]
    const float* __restrict__ im_info,    // [B,6]
    const float* __restrict__ gtp_all,    // [B,Gp,8] prepped
    int A, int Gp,
    double* __restrict__ ws)
{
#pragma clang fp contract(off)
    const int b = blockIdx.y;
    const int t = blockIdx.x * 256 + threadIdx.x;
    const int base_raw = 2 * t;
    const bool live0 = base_raw < A;
    const bool live1 = base_raw + 1 < A;
    const int base = min(base_raw, A - 2);       // clamped: uniform control flow
    const float* __restrict__ gtp = gtp_all + (size_t)b * Gp * 8;
    const int nvalid = __builtin_amdgcn_readfirstlane((int)im_info[b * 6 + 5]);
    const int ntiles = (nvalid + 3) >> 2;        // sentinels cover the tail

    const float4 ancA = *reinterpret_cast<const float4*>(anchors + 4 * (size_t)base);
    const float4 ancB = *reinterpret_cast<const float4*>(anchors + 4 * ((size_t)base + 1));
    const float awA = ancA.z - ancA.x + 1.f, ahA = ancA.w - ancA.y + 1.f;
    const float awB = ancB.z - ancB.x + 1.f, ahB = ancB.w - ancB.y + 1.f;
    const float areaA = awA * ahA, areaB = awB * ahB;
    const float a2pA = ancA.z + 1.f, a3pA = ancA.w + 1.f;   // +1 pre-added
    const float a2pB = ancB.z + 1.f, a3pB = ancB.w + 1.f;

    // Division-free IoU argmax: iou = inter/(S-inter) monotone in inter/S =>
    // iou_i > iou_j  <=>  inter_i*S_j > inter_j*S_i (S>0). Init (-1,1) makes
    // the first gt always win; strict > == first-max (jnp.argmax tie-break).
    float biA = -1.f, bSA = 1.f; int argA = 0;
    float biB = -1.f, bSB = 1.f; int argB = 0;

    for (int tt = 0; tt < ntiles; ++tt) {
        const float* tp = gtp + (size_t)tt * 32;     // 4 gts * 8 floats
        #pragma unroll
        for (int j = 0; j < 4; ++j) {
            // Same-address 64-lane broadcast load (L1-hot), then pin to SGPRs.
            const float4 q = *reinterpret_cast<const float4*>(tp + j * 8);
            const float sgl = tp[j * 8 + 4];
            const float g0  = rflf(q.x);
            const float g1  = rflf(q.y);
            const float g2p = rflf(q.z);
            const float g3p = rflf(q.w);
            const float sg  = rflf(sgl);
            const int gidx = tt * 4 + j;
            {
                const float iw = fminf(a2pA, g2p) - fmaxf(ancA.x, g0);
                const float ih = fminf(a3pA, g3p) - fmaxf(ancA.y, g1);
                const float inter = fmaxf(iw, 0.f) * fmaxf(ih, 0.f);
                const float S = areaA + sg;
                const bool upd = inter * bSA > biA * S;
                biA  = upd ? inter : biA;
                bSA  = upd ? S     : bSA;
                argA = upd ? gidx  : argA;
            }
            {
                const float iw = fminf(a2pB, g2p) - fmaxf(ancB.x, g0);
                const float ih = fminf(a3pB, g3p) - fmaxf(ancB.y, g1);
                const float inter = fmaxf(iw, 0.f) * fmaxf(ih, 0.f);
                const float S = areaB + sg;
                const bool upd = inter * bSB > biB * S;
                biB  = upd ? inter : biB;
                bSB  = upd ? S     : bSB;
                argB = upd ? gidx  : argB;
            }
        }
    }

    float lc = 0.f, lr = 0.f;
    int fg = 0;
    const size_t baseA = (size_t)b * A + base;
    epilogue(live0, ancA.x, ancA.y, awA, ahA, biA, bSA, argA,
             gtp, pred_cls + baseA, pred_reg + 4 * baseA, lc, lr, fg);
    epilogue(live1, ancB.x, ancB.y, awB, ahB, biB, bSB, argB,
             gtp, pred_cls + baseA + 1, pred_reg + 4 * (baseA + 1), lc, lr, fg);

    // wave64 reduction
    for (int off = 32; off > 0; off >>= 1) {
        lc += __shfl_down(lc, off);
        lr += __shfl_down(lr, off);
        fg += __shfl_down(fg, off);
    }

    __shared__ float s_lc[4], s_lr[4];
    __shared__ int s_np[4];
    const int wid = threadIdx.x >> 6;
    const int lane = threadIdx.x & 63;
    if (lane == 0) { s_lc[wid] = lc; s_lr[wid] = lr; s_np[wid] = fg; }
    __syncthreads();
    if (threadIdx.x == 0) {
        const float tlc = s_lc[0] + s_lc[1] + s_lc[2] + s_lc[3];
        const float tlr = s_lr[0] + s_lr[1] + s_lr[2] + s_lr[3];
        const int   tnp = s_np[0] + s_np[1] + s_np[2] + s_np[3];
        __hip_atomic_fetch_add(&ws[0], (double)tlc, __ATOMIC_RELAXED, __HIP_MEMORY_SCOPE_AGENT);
        __hip_atomic_fetch_add(&ws[1], (double)tlr, __ATOMIC_RELAXED, __HIP_MEMORY_SCOPE_AGENT);
        __hip_atomic_fetch_add(&ws[2], (double)tnp, __ATOMIC_RELAXED, __HIP_MEMORY_SCOPE_AGENT);
    }
}

__global__ void finalize_kernel(const double* __restrict__ ws, float* __restrict__ out) {
    if (threadIdx.x == 0 && blockIdx.x == 0) {
        const double npos = ws[2] < 1.0 ? 1.0 : ws[2];
        const double norm = 0.9 * 100.0 + 0.1 * npos;
        out[0] = (float)(ws[0] / norm);
        out[1] = (float)(ws[1] / norm);
    }
}

extern "C" void kernel_launch(void* const* d_in, const int* in_sizes, int n_in,
                              void* d_out, int out_size, void* d_ws, size_t ws_size,
                              hipStream_t stream) {
    const float* pred_cls = (const float*)d_in[0];
    const float* pred_reg = (const float*)d_in[1];
    const float* anchors  = (const float*)d_in[2];
    const float* gt_boxes = (const float*)d_in[3];
    const float* im_info  = (const float*)d_in[4];

    const int A = in_sizes[2] / 4;
    const int B = in_sizes[4] / 6;
    const int G = in_sizes[3] / (B * 5);
    const int Gp = (G + 3) & ~3;                 // pad to tile multiple

    double* ws = (double*)d_ws;
    float*  gtp = (float*)((char*)d_ws + WS_GT_BYTE_OFF);

    const int total_gt = B * Gp;
    prep_gt_kernel<<<(total_gt + 255) / 256, 256, 0, stream>>>(
        gt_boxes, im_info, gtp, ws, G, Gp, B);

    const int threads_per_b = (A + 1) / 2;
    dim3 grid((threads_per_b + 255) / 256, B);
    retina_loss_kernel<<<grid, 256, 0, stream>>>(
        pred_cls, pred_reg, anchors, im_info, gtp, A, Gp, ws);
    finalize_kernel<<<1, 1, 0, stream>>>(ws, (float*)d_out);
}